// Round 17
// baseline (274.541 us; speedup 1.0000x reference)
//
#include <hip/hip_runtime.h>
#include <stdint.h>

#define DIN    100
#define DCODE  1000
#define ROWU   100
#define WCAP   12
#define ZTHR   1.70f
#define RCAP   48      // key slots per (row, half) region

typedef float f32x16 __attribute__((ext_vector_type(16)));
typedef short s16x8 __attribute__((ext_vector_type(8)));

// ws layout (bytes)
#define OFF_CTR   0
#define OFF_LST   64
#define IMG_BYTES (32 * 16384)              // hi/lo image: 16KB per 32-code chunk
#define OFF_IMG   524352                    // 64 + fix-list (131072*4)
#define WDT_BYTES (1024 * 128 * 4)
#define OFF_WDT   (OFF_IMG + IMG_BYTES)
#define WS_NEED   (OFF_WDT + WDT_BYTES)

__device__ __forceinline__ uint16_t f2bf(float v) {
  uint32_t u = __float_as_uint(v);
  return (uint16_t)((u + 0x7FFFu + ((u >> 16) & 1u)) >> 16);
}
__device__ __forceinline__ float bf2f(uint16_t h) {
  return __uint_as_float(((uint32_t)h) << 16);
}
// POSITIVE-value packed key: float bits with code id in low 10 mantissa bits.
// Valid because every candidate has v >= t0 > 0. Truncation <= 1023 ulp
// (<= ~5e-4 for v < 4) covered by the 1e-3 slack in thr/eps.
__device__ __forceinline__ uint32_t packkey(float v, uint32_t c) {
  return (__float_as_uint(v) & 0xFFFFFC00u) | c;
}
__device__ __forceinline__ float unpackkey(uint32_t m) {
  return __uint_as_float(m & 0xFFFFFC00u);
}

typedef __attribute__((address_space(1))) const uint32_t GU32;
typedef __attribute__((address_space(3))) uint32_t LU32;
__device__ __forceinline__ void gload_lds16(const void* g, void* l) {
  __builtin_amdgcn_global_load_lds((GU32*)g, (LU32*)l, 16, 0, 0);
}

// ---------------------------------------------------------------------------
// prep: swizzled chunk-major bf16 hi/lo We image (32 chunks x [hi 8K | lo 8K]),
// bias baked at k=100 (pad codes -1000); WdT transpose padded to stride 128;
// fix ctr = 0. Swizzle: byte L = c_local*256 + 2k stored at L ^ ((cl&7)<<4).
// ---------------------------------------------------------------------------
__global__ __launch_bounds__(256) void prep_k(
    const float* __restrict__ We, const float* __restrict__ be,
    const float* __restrict__ Wd, uint8_t* __restrict__ img,
    float* __restrict__ wdt, uint32_t* __restrict__ ctr) {
  int idx = blockIdx.x * 256 + threadIdx.x;
  if (idx == 0) *ctr = 0u;
  if (idx < 1024 * 128) {
    int c = idx >> 7, k = idx & 127;
    float v = 0.f;
    if (k < DIN) v = (c < DCODE) ? We[c * DIN + k] : 0.f;
    else if (k == DIN) v = (c < DCODE) ? be[c] : -1000.f;
    uint16_t h = f2bf(v);
    uint16_t l = f2bf(v - bf2f(h));
    int ch = c >> 5, cl = c & 31;
    int L = cl * 256 + k * 2;
    int S = L ^ ((cl & 7) << 4);
    uint8_t* base = img + ch * 16384;
    *(uint16_t*)(base + S) = h;
    *(uint16_t*)(base + 8192 + S) = l;
    wdt[idx] = (k < DIN && c < DCODE) ? Wd[k * DCODE + c] : 0.f;
  }
}

// ---------------------------------------------------------------------------
// screen_k v17 = v16 with launch_bounds (512, 6): 6 waves/EU -> k = 6*4/8 =
// 3 blocks/CU = 24 waves/CU (LDS 3x48KB = 144KB <= 160KB; VGPR 64 -> fits).
// T3/T4 counted-vmcnt triple-buffer pipeline; 8 waves x 32 rows = 256
// rows/block; prefetch distance 2; s_waitcnt vmcnt(2) + raw s_barrier per
// chunk (full drain only at ch=30). Per chunk: 21 MFMA (7 K-steps x 3 hi/lo
// passes of 32x32x16), per-lane filter into 48-slot region.
// ---------------------------------------------------------------------------
__global__ __launch_bounds__(512, 6) void screen_k(
    const float* __restrict__ x, const uint8_t* __restrict__ img,
    uint32_t* __restrict__ cand) {
  __shared__ __align__(16) uint8_t sbuf[3][16384];
  int tid = threadIdx.x, lane = tid & 63, w = tid >> 6;
  int h = lane >> 5, r32 = lane & 31;
  int row = blockIdx.x * 256 + w * 32 + r32;

  // B fragments (x row, bf16 hi/lo), 7 ksteps of K=16 (this lane's 8-elem half)
  s16x8 Bh[7], Bl[7];
  const float* xr = x + (size_t)row * DIN;
  float sq = 0.f;
#pragma unroll
  for (int ks = 0; ks < 7; ++ks) {
    int k0 = ks * 16 + h * 8;
    float v[8];
    if (ks < 6) {
      float4 a = *(const float4*)(xr + k0);
      float4 b = *(const float4*)(xr + k0 + 4);
      v[0] = a.x; v[1] = a.y; v[2] = a.z; v[3] = a.w;
      v[4] = b.x; v[5] = b.y; v[6] = b.z; v[7] = b.w;
    } else if (h == 0) {              // k = 96..103: x96..99, bias, zeros
      float4 a = *(const float4*)(xr + 96);
      v[0] = a.x; v[1] = a.y; v[2] = a.z; v[3] = a.w;
      v[4] = 1.f; v[5] = 0.f; v[6] = 0.f; v[7] = 0.f;
    } else {                          // k = 104..111: zeros
#pragma unroll
      for (int j = 0; j < 8; ++j) v[j] = 0.f;
    }
    s16x8 hv, lv;
#pragma unroll
    for (int j = 0; j < 8; ++j) {
      sq = fmaf(v[j], v[j], sq);
      uint16_t hb = f2bf(v[j]);
      hv[j] = (short)hb;
      lv[j] = (short)f2bf(v[j] - bf2f(hb));
    }
    Bh[ks] = hv; Bl[ks] = lv;
  }
  sq += __shfl_xor(sq, 32);           // pair covers disjoint k-halves of the row
  float sr = sqrtf(sq);               // sqrt(||x||^2 + 1)
  float eb = 2e-5f * sr + 5e-5f;      // 3-pass screen error bound
  float t0 = ZTHR * 0.057735f * sr - eb;

  uint32_t tc = 0;
  uint32_t* rb = cand + (size_t)row * ROWU + h * RCAP;

  // prologue: stage chunks 0 and 1 (each wave stages its 2KB slice of each)
  {
    const uint8_t* s0 = img + w * 2048 + lane * 16;
    uint8_t* d0 = &sbuf[0][w * 2048 + lane * 16];
    gload_lds16(s0, d0);
    gload_lds16(s0 + 1024, d0 + 1024);
    const uint8_t* s1 = img + 16384 + w * 2048 + lane * 16;
    uint8_t* d1 = &sbuf[1][w * 2048 + lane * 16];
    gload_lds16(s1, d1);
    gload_lds16(s1 + 1024, d1 + 1024);
  }
  __syncthreads();

  for (int ch = 0; ch < 32; ++ch) {
    // stage chunk ch+2 into buf (ch+2)%3 (last read at iter ch-1; safe after
    // the end-of-(ch-1) barrier)
    if (ch < 30) {
      const uint8_t* src = img + (ch + 2) * 16384 + w * 2048 + lane * 16;
      uint8_t* dst = &sbuf[(ch + 2) % 3][w * 2048 + lane * 16];
      gload_lds16(src, dst);
      gload_lds16(src + 1024, dst + 1024);
    }
    const uint8_t* bb = sbuf[ch % 3];
    f32x16 acc = {};
#pragma unroll
    for (int ks = 0; ks < 7; ++ks) {
      int S = (r32 * 256 + ks * 32 + h * 16) ^ ((r32 & 7) << 4);
      s16x8 ah = *(const s16x8*)(bb + S);
      s16x8 al = *(const s16x8*)(bb + 8192 + S);
      acc = __builtin_amdgcn_mfma_f32_32x32x16_bf16(ah, Bh[ks], acc, 0, 0, 0);
      acc = __builtin_amdgcn_mfma_f32_32x32x16_bf16(ah, Bl[ks], acc, 0, 0, 0);
      acc = __builtin_amdgcn_mfma_f32_32x32x16_bf16(al, Bh[ks], acc, 0, 0, 0);
    }
    uint32_t cb = (uint32_t)(ch * 32 + 4 * h);
#pragma unroll
    for (int reg = 0; reg < 16; ++reg) {
      float v = acc[reg];
      if (v >= t0) {
        if (tc < (uint32_t)RCAP)
          rb[tc] = packkey(v, cb + (uint32_t)((reg & 3) + 8 * (reg >> 2)));
        tc++;
      }
    }
    // counted-vmcnt barrier: chunk ch+1's loads (issued at ch-1) are older
    // than this iter's 2 loads -> retired once outstanding <= 2. Only ch=30
    // (no new loads) needs a full drain for chunk 31.
    if (ch < 31) {
      if (ch == 30) asm volatile("s_waitcnt vmcnt(0)" ::: "memory");
      else          asm volatile("s_waitcnt vmcnt(2)" ::: "memory");
      __builtin_amdgcn_s_barrier();
    }
  }
  // header: counts for the two halves + thr + eb (one uint4 per row)
  uint32_t b0 = tc > 255u ? 255u : tc;
  uint32_t c1 = __shfl(b0, (lane & 31) + 32);
  if (lane < 32) {
    uint32_t* rowp = cand + (size_t)row * ROWU;
    float thr = t0 + 2.f * eb + 1e-3f;    // miss hazard + key trunc slack
    *(uint4*)(rowp + 96) = make_uint4(b0 | (c1 << 8), __float_as_uint(thr),
                                      __float_as_uint(eb), 0u);
  }
}

// ---------------------------------------------------------------------------
// select_decode_k: one row per HALF-WAVE (8 rows / 256-thr block). Two 48-slot
// regions per row; each lane owns 3 key slots; compaction + dynamic uint4 rank
// loop -> exact 25th key; fp64 re-rank only when >1 key in +-eps window;
// decode = 25 lanes x float4.
// ---------------------------------------------------------------------------
__global__ __launch_bounds__(256) void select_decode_k(
    const float* __restrict__ x, const float* __restrict__ We,
    const float* __restrict__ be, const float* __restrict__ bd,
    const float* __restrict__ wdt, float* __restrict__ out,
    uint32_t* __restrict__ fix_ctr, uint32_t* __restrict__ fix_list) {
  __shared__ uint32_t skeys[8][104];
  __shared__ uint2    selp[8][26];
  __shared__ double   wvalS[8][WCAP];
  __shared__ int      widS[8][WCAP];

  int tid = threadIdx.x, l32 = tid & 31, wi = tid >> 5;
  int lbase = (wi & 1) * 32;               // this half's bit offset in wave ballots
  uint32_t ltm32 = (l32 == 31) ? 0x7FFFFFFFu : ((1u << l32) - 1u);
  int row = blockIdx.x * 8 + wi;
  uint32_t* rowp = (uint32_t*)out + (size_t)row * ROWU;

  uint32_t hdr = rowp[96];
  float thrp = __uint_as_float(rowp[97]);
  float eb = __uint_as_float(rowp[98]);
  uint32_t c0 = hdr & 255u, c1 = (hdr >> 8) & 255u;
  uint32_t total = c0 + c1;
  bool bad = (c0 > (uint32_t)RCAP) || (c1 > (uint32_t)RCAP) || (total < 25u);

  uint32_t k0 = 0u, k1 = 0u, k2 = 0u, tau = 0u;
  int r0 = 0, r1 = 0, r2 = 0;
  float vtau = 0.f;
  if (!bad) {
    // slot -> (region, in-region idx): region0 = slots [0,48), region1 = [48,96)
    bool g1r0 = (l32 < 16);                        // slot 32+l32 in region0?
    uint32_t i0 = (uint32_t)l32;                   // region0
    uint32_t i1 = g1r0 ? (uint32_t)(32 + l32) : (uint32_t)(l32 - 16);
    uint32_t i2 = (uint32_t)(16 + l32);            // region1
    k0 = (i0 < c0) ? rowp[l32] : 0u;
    k1 = (i1 < (g1r0 ? c0 : c1)) ? rowp[32 + l32] : 0u;
    k2 = (i2 < c1) ? rowp[64 + l32] : 0u;
    // zero + compact (zeros inert: real keys are positive floats >= t0 > 0)
    skeys[wi][l32] = 0u; skeys[wi][32 + l32] = 0u; skeys[wi][64 + l32] = 0u;
    if (k0) skeys[wi][i0] = k0;
    if (k1) skeys[wi][(g1r0 ? 0u : c0) + i1] = k1;
    if (k2) skeys[wi][c0 + i2] = k2;
    // dynamic rank loop (~ceil(total/4) iters)
    int nq = ((int)total + 3) >> 2;
    const uint4* sp = (const uint4*)skeys[wi];
    for (int j = 0; j < nq; ++j) {
      uint4 q = sp[j];
      r0 += (q.x > k0) + (q.y > k0) + (q.z > k0) + (q.w > k0);
      r1 += (q.x > k1) + (q.y > k1) + (q.z > k1) + (q.w > k1);
      r2 += (q.x > k2) + (q.y > k2) + (q.z > k2) + (q.w > k2);
    }
    // tau = key of rank 24 (exists since total >= 25, keys unique)
    uint32_t h0 = (uint32_t)(__ballot(k0 != 0u && r0 == 24) >> lbase);
    uint32_t h1 = (uint32_t)(__ballot(k1 != 0u && r1 == 24) >> lbase);
    uint32_t h2 = (uint32_t)(__ballot(k2 != 0u && r2 == 24) >> lbase);
    if (h0)      tau = __shfl(k0, lbase + (__ffs(h0) - 1));
    else if (h1) tau = __shfl(k1, lbase + (__ffs(h1) - 1));
    else         tau = __shfl(k2, lbase + (__ffs(h2) - 1));
    vtau = unpackkey(tau);
    if (vtau < thrp) bad = true;           // possible missed-top-25 -> exact path
  }
  if (bad && l32 == 0) { uint32_t p = atomicAdd(fix_ctr, 1u); fix_list[p] = (uint32_t)row; }
  bool alive = !bad;

  float eps = 2.f * eb + 1e-3f;            // screen err both sides + key trunc
  float v0 = unpackkey(k0), v1 = unpackkey(k1), v2 = unpackkey(k2);
  bool in0 = k0 != 0u, in1 = k1 != 0u, in2 = k2 != 0u;
  bool w0 = in0 && fabsf(v0 - vtau) <= eps;
  bool w1 = in1 && fabsf(v1 - vtau) <= eps;
  bool w2 = in2 && fabsf(v2 - vtau) <= eps;
  uint32_t W0 = (uint32_t)(__ballot(w0) >> lbase);
  uint32_t W1 = (uint32_t)(__ballot(w1) >> lbase);
  uint32_t W2 = (uint32_t)(__ballot(w2) >> lbase);
  int nwin = __popc(W0) + __popc(W1) + __popc(W2);

  bool f0 = false, f1 = false, f2 = false;
  float fv0 = v0, fv1 = v1, fv2 = v2;
  bool bad2 = false;
  if (alive) {
    if (nwin == 1) {
      // window holds only tau itself: screen ranking is exact
      f0 = in0 && (r0 < 25); f1 = in1 && (r1 < 25); f2 = in2 && (r2 < 25);
    } else {
      bool s0 = in0 && (r0 < 25) && !w0;
      bool s1 = in1 && (r1 < 25) && !w1;
      bool s2 = in2 && (r2 < 25) && !w2;
      int ndef = __popc((uint32_t)(__ballot(s0) >> lbase)) +
                 __popc((uint32_t)(__ballot(s1) >> lbase)) +
                 __popc((uint32_t)(__ballot(s2) >> lbase));
      int need = 25 - ndef;
      if (nwin > WCAP || need < 0 || need > nwin) {
        bad2 = true;
      } else {
        int j0 = __popc(W0 & ltm32);
        int j1 = __popc(W0) + __popc(W1 & ltm32);
        int j2 = __popc(W0) + __popc(W1) + __popc(W2 & ltm32);
        if (w0) widS[wi][j0] = (int)(k0 & 1023u);
        if (w1) widS[wi][j1] = (int)(k1 & 1023u);
        if (w2) widS[wi][j2] = (int)(k2 & 1023u);
        const float* xr = x + (size_t)row * DIN;
        for (int j = 0; j < nwin; ++j) {
          int id = widS[wi][j];
          const float* wr = We + (size_t)id * DIN;
          double p = (double)xr[l32] * (double)wr[l32];
          p += (double)xr[l32 + 32] * (double)wr[l32 + 32];
          p += (double)xr[l32 + 64] * (double)wr[l32 + 64];
          if (l32 < 4) p += (double)xr[l32 + 96] * (double)wr[l32 + 96];
#pragma unroll
          for (int o = 1; o < 32; o <<= 1) p += __shfl_xor(p, o);
          if (l32 == 0) wvalS[wi][j] = p + (double)be[id];
        }
        uint32_t chosen = 0u;
        for (int j = 0; j < nwin; ++j) {
          double vj = wvalS[wi][j]; int idj = widS[wi][j];
          int rank = 0;
          for (int l2 = 0; l2 < nwin; ++l2) {
            double vl = wvalS[wi][l2]; int idl = widS[wi][l2];
            rank += (vl > vj || (vl == vj && idl < idj)) ? 1 : 0;
          }
          if (rank < need) chosen |= (1u << j);
        }
        bool ch0 = w0 && ((chosen >> j0) & 1u);
        bool ch1 = w1 && ((chosen >> j1) & 1u);
        bool ch2 = w2 && ((chosen >> j2) & 1u);
        if (ch0) fv0 = (float)wvalS[wi][j0];
        if (ch1) fv1 = (float)wvalS[wi][j1];
        if (ch2) fv2 = (float)wvalS[wi][j2];
        f0 = s0 || ch0; f1 = s1 || ch1; f2 = s2 || ch2;
      }
    }
  }
  if (bad2) {
    if (l32 == 0) { uint32_t p = atomicAdd(fix_ctr, 1u); fix_list[p] = (uint32_t)row; }
    alive = false;
  }

  if (l32 < 26) selp[wi][l32] = make_uint2(0u, 0u);
  uint32_t F0 = (uint32_t)(__ballot(alive && f0) >> lbase);
  uint32_t F1 = (uint32_t)(__ballot(alive && f1) >> lbase);
  uint32_t F2 = (uint32_t)(__ballot(alive && f2) >> lbase);
  int p0 = __popc(F0 & ltm32);
  int p1 = __popc(F0) + __popc(F1 & ltm32);
  int p2 = __popc(F0) + __popc(F1) + __popc(F2 & ltm32);
  if (alive && f0 && p0 < 25) selp[wi][p0] = make_uint2(__float_as_uint(fv0), k0 & 1023u);
  if (alive && f1 && p1 < 25) selp[wi][p1] = make_uint2(__float_as_uint(fv1), k1 & 1023u);
  if (alive && f2 && p2 < 25) selp[wi][p2] = make_uint2(__float_as_uint(fv2), k2 & 1023u);

  if (alive) {
    uint4 s4[13];
    const uint4* sq = (const uint4*)selp[wi];
#pragma unroll
    for (int j = 0; j < 13; ++j) s4[j] = sq[j];
    const uint32_t* sw = (const uint32_t*)s4;
    float4 a = make_float4(0.f, 0.f, 0.f, 0.f);
    if (l32 < 25) a = *(const float4*)(bd + 4 * l32);
#pragma unroll
    for (int j = 0; j < 25; ++j) {
      float v = __uint_as_float(sw[2 * j]);
      uint32_t id = sw[2 * j + 1];
      if (l32 < 25) {
        float4 wv = *(const float4*)(wdt + ((size_t)id << 7) + 4 * l32);
        a.x = fmaf(v, wv.x, a.x);
        a.y = fmaf(v, wv.y, a.y);
        a.z = fmaf(v, wv.z, a.z);
        a.w = fmaf(v, wv.w, a.w);
      }
    }
    if (l32 < 25) *(float4*)(out + (size_t)row * DIN + 4 * l32) = a;
  }
}

// ---------------------------------------------------------------------------
// fix_k: exact fp64 full pipeline for punted rows (expected few hundred).
// ---------------------------------------------------------------------------
__global__ __launch_bounds__(256) void fix_k(
    const float* __restrict__ x, const float* __restrict__ We,
    const float* __restrict__ be, const float* __restrict__ bd,
    const float* __restrict__ wdt, float* __restrict__ out,
    const uint32_t* __restrict__ fix_ctr, const uint32_t* __restrict__ fix_list) {
  __shared__ float xs[DIN];
  __shared__ unsigned long long keys[1024];
  __shared__ float dv[25];
  __shared__ int   di[25];
  int tid = threadIdx.x;
  int n = (int)*fix_ctr;
  for (int it = blockIdx.x; it < n; it += gridDim.x) {
    int row = (int)fix_list[it];
    __syncthreads();
    if (tid < DIN) xs[tid] = x[(size_t)row * DIN + tid];
    __syncthreads();
    for (int c = tid; c < 1024; c += 256) {
      unsigned long long kk = 0ull;
      if (c < DCODE) {
        double a = 0.0;
        for (int k = 0; k < DIN; ++k)
          a = fma((double)xs[k], (double)We[(size_t)c * DIN + k], a);
        a += (double)be[c];
        unsigned long long uu = (unsigned long long)__double_as_longlong(a);
        uu ^= ((unsigned long long)((long long)uu >> 63)) | 0x8000000000000000ull;
        kk = (uu & ~1023ull) | (unsigned long long)c;
      }
      keys[c] = kk;
    }
    __syncthreads();
    if (tid < 64) {
      for (int p = 0; p < 25; ++p) {
        unsigned long long mx = 0ull;
        for (int j = 0; j < 16; ++j) {
          unsigned long long v = keys[tid * 16 + j];
          if (v > mx) mx = v;
        }
#pragma unroll
        for (int off = 32; off > 0; off >>= 1) {
          unsigned long long o = (unsigned long long)__shfl_xor((long long)mx, off, 64);
          if (o > mx) mx = o;
        }
        if (tid == 0) {
          int id = (int)(mx & 1023ull);
          unsigned long long ub =
              (mx & 0x8000000000000000ull) ? (mx & 0x7FFFFFFFFFFFFFFFull) : ~mx;
          dv[p] = (float)__longlong_as_double((long long)ub);
          di[p] = id;
          keys[id] = 0ull;
        }
      }
    }
    __syncthreads();
    if (tid < DIN) {
      float a = bd[tid];
      for (int p = 0; p < 25; ++p)
        a = fmaf(dv[p], wdt[((size_t)di[p] << 7) + tid], a);
      out[(size_t)row * DIN + tid] = a;
    }
  }
}

// ============================================================================
// Fallback path (round-1, known-pass)
// ============================================================================
__global__ __launch_bounds__(256) void transpose_wdec_k(const float* __restrict__ Wd,
                                                        float* __restrict__ WdT) {
  int idx = blockIdx.x * 256 + threadIdx.x;
  if (idx < DIN * DCODE) {
    int c = idx / DIN;
    int j = idx - c * DIN;
    WdT[idx] = Wd[j * DCODE + c];
  }
}

#define FKEEP 28
__global__ __launch_bounds__(256) void sae_topk_fused(
    const float* __restrict__ x, const float* __restrict__ We,
    const float* __restrict__ be, const float* __restrict__ Wd,
    const float* __restrict__ bd, const float* __restrict__ WdT,
    float* __restrict__ out, int nrows) {
  int row = blockIdx.x * 256 + threadIdx.x;
  if (row >= nrows) return;
  float xv[DIN];
  {
    const float4* x4 = reinterpret_cast<const float4*>(x + (size_t)row * DIN);
#pragma unroll
    for (int i = 0; i < DIN / 4; ++i) {
      float4 v = x4[i];
      xv[4 * i] = v.x; xv[4 * i + 1] = v.y; xv[4 * i + 2] = v.z; xv[4 * i + 3] = v.w;
    }
  }
  uint32_t keys[FKEEP];
#pragma unroll
  for (int j = 0; j < FKEEP; ++j) keys[j] = 0u;
  for (int c = 0; c < DCODE; ++c) {
    const float4* w4 = reinterpret_cast<const float4*>(We + c * DIN);
    float pp0 = be[c], pp1 = 0.f, pp2 = 0.f, pp3 = 0.f;
#pragma unroll
    for (int i = 0; i < DIN / 4; ++i) {
      float4 wv = w4[i];
      pp0 = fmaf(wv.x, xv[4 * i], pp0);
      pp1 = fmaf(wv.y, xv[4 * i + 1], pp1);
      pp2 = fmaf(wv.z, xv[4 * i + 2], pp2);
      pp3 = fmaf(wv.w, xv[4 * i + 3], pp3);
    }
    float h = (pp0 + pp1) + (pp2 + pp3);
    uint32_t u = __float_as_uint(h);
    u ^= ((uint32_t)((int32_t)u >> 31)) | 0x80000000u;
    uint32_t key = (u & 0xFFFFFC00u) | (uint32_t)c;
    if (key > keys[FKEEP - 1]) {
#pragma unroll
      for (int j = FKEEP - 1; j > 0; --j)
        keys[j] = (key > keys[j]) ? ((key > keys[j - 1]) ? keys[j - 1] : key) : keys[j];
      keys[0] = (key > keys[0]) ? key : keys[0];
    }
  }
  double v64[FKEEP];
#pragma unroll
  for (int kq = 0; kq < FKEEP; ++kq) {
    int c = (int)(keys[kq] & 1023u);
    const float4* w4 = reinterpret_cast<const float4*>(We + c * DIN);
    double aa0 = 0.0, aa1 = 0.0;
#pragma unroll
    for (int i = 0; i < DIN / 4; ++i) {
      float4 wv = w4[i];
      aa0 = fma((double)wv.x, (double)xv[4 * i], aa0);
      aa1 = fma((double)wv.y, (double)xv[4 * i + 1], aa1);
      aa0 = fma((double)wv.z, (double)xv[4 * i + 2], aa0);
      aa1 = fma((double)wv.w, (double)xv[4 * i + 3], aa1);
    }
    double h = (aa0 + aa1) + (double)be[c];
    uint64_t u = (uint64_t)__double_as_longlong(h);
    u = (u & ~1023ull) | (uint64_t)(uint32_t)c;
    v64[kq] = __longlong_as_double((int64_t)u);
  }
#pragma unroll
  for (int p = 0; p < FKEEP - 1; ++p) {
#pragma unroll
    for (int j = 0; j < FKEEP - 1 - p; ++j) {
      double a = v64[j], b2 = v64[j + 1];
      v64[j] = fmax(a, b2);
      v64[j + 1] = fmin(a, b2);
    }
  }
  float acc[DIN];
  {
    const float4* b4 = reinterpret_cast<const float4*>(bd);
#pragma unroll
    for (int i = 0; i < DIN / 4; ++i) {
      float4 v = b4[i];
      acc[4 * i] = v.x; acc[4 * i + 1] = v.y; acc[4 * i + 2] = v.z; acc[4 * i + 3] = v.w;
    }
  }
  if (WdT) {
#pragma unroll
    for (int kq = 0; kq < 25; ++kq) {
      int c = (int)((uint64_t)__double_as_longlong(v64[kq]) & 1023ull);
      float hv = (float)v64[kq];
      const float4* w4 = reinterpret_cast<const float4*>(WdT + c * DIN);
#pragma unroll
      for (int i = 0; i < DIN / 4; ++i) {
        float4 wv = w4[i];
        acc[4 * i]     = fmaf(hv, wv.x, acc[4 * i]);
        acc[4 * i + 1] = fmaf(hv, wv.y, acc[4 * i + 1]);
        acc[4 * i + 2] = fmaf(hv, wv.z, acc[4 * i + 2]);
        acc[4 * i + 3] = fmaf(hv, wv.w, acc[4 * i + 3]);
      }
    }
  } else {
#pragma unroll
    for (int kq = 0; kq < 25; ++kq) {
      int c = (int)((uint64_t)__double_as_longlong(v64[kq]) & 1023ull);
      float hv = (float)v64[kq];
      for (int j = 0; j < DIN; ++j)
        acc[j] = fmaf(hv, Wd[j * DCODE + c], acc[j]);
    }
  }
  float4* o4 = reinterpret_cast<float4*>(out + (size_t)row * DIN);
#pragma unroll
  for (int i = 0; i < DIN / 4; ++i)
    o4[i] = make_float4(acc[4 * i], acc[4 * i + 1], acc[4 * i + 2], acc[4 * i + 3]);
}

// ============================================================================
extern "C" void kernel_launch(void* const* d_in, const int* in_sizes, int n_in,
                              void* d_out, int out_size, void* d_ws, size_t ws_size,
                              hipStream_t stream) {
  const float* x  = (const float*)d_in[0];
  const float* We = (const float*)d_in[1];
  const float* be = (const float*)d_in[2];
  const float* Wd = (const float*)d_in[3];
  const float* bd = (const float*)d_in[4];
  int nrows = in_sizes[0] / DIN;

  bool shape_ok = (in_sizes[1] == DCODE * DIN) && (in_sizes[2] == DCODE) &&
                  (in_sizes[3] == DIN * DCODE) && (nrows % 256 == 0) &&
                  (nrows <= 131072);
  if (shape_ok && ws_size >= (size_t)WS_NEED) {
    char* wsb = (char*)d_ws;
    uint32_t* ctr = (uint32_t*)(wsb + OFF_CTR);
    uint32_t* lst = (uint32_t*)(wsb + OFF_LST);
    uint8_t*  img = (uint8_t*)(wsb + OFF_IMG);
    float*    wdt = (float*)(wsb + OFF_WDT);

    prep_k<<<512, 256, 0, stream>>>(We, be, Wd, img, wdt, ctr);
    screen_k<<<nrows / 256, 512, 0, stream>>>(x, img, (uint32_t*)d_out);
    select_decode_k<<<nrows / 8, 256, 0, stream>>>(x, We, be, bd, wdt, (float*)d_out, ctr, lst);
    fix_k<<<512, 256, 0, stream>>>(x, We, be, bd, wdt, (float*)d_out, ctr, lst);
  } else {
    float* WdT = nullptr;
    if (ws_size >= (size_t)(DIN * DCODE * sizeof(float))) {
      WdT = (float*)d_ws;
      transpose_wdec_k<<<(DIN * DCODE + 255) / 256, 256, 0, stream>>>(Wd, WdT);
    }
    int nb = (nrows + 255) / 256;
    sae_topk_fused<<<nb, 256, 0, stream>>>(x, We, be, Wd, bd, WdT, (float*)d_out, nrows);
  }
}

// Round 18
// 224.252 us; speedup vs baseline: 1.2243x; 1.2243x over previous
//
#include <hip/hip_runtime.h>
#include <stdint.h>

#define DIN    100
#define DCODE  1000
#define ROWU   100
#define WCAP   12
#define ZTHR   1.70f
#define RCAP   48      // key slots per (row, half) region

typedef float f32x16 __attribute__((ext_vector_type(16)));
typedef short s16x8 __attribute__((ext_vector_type(8)));

// ws layout (bytes)
#define OFF_CTR   0
#define OFF_LST   64
#define IMG_BYTES (32 * 16384)              // hi/lo image: 16KB per 32-code chunk
#define OFF_IMG   524352                    // 64 + fix-list (131072*4)
#define WDT_BYTES (1024 * 128 * 4)
#define OFF_WDT   (OFF_IMG + IMG_BYTES)
#define WS_NEED   (OFF_WDT + WDT_BYTES)

__device__ __forceinline__ uint16_t f2bf(float v) {
  uint32_t u = __float_as_uint(v);
  return (uint16_t)((u + 0x7FFFu + ((u >> 16) & 1u)) >> 16);
}
__device__ __forceinline__ float bf2f(uint16_t h) {
  return __uint_as_float(((uint32_t)h) << 16);
}
// POSITIVE-value packed key: float bits with code id in low 10 mantissa bits.
// Valid because every candidate has v >= t0 > 0. Truncation <= 1023 ulp
// (<= ~5e-4 for v < 4) covered by the 1e-3 slack in thr/eps.
__device__ __forceinline__ uint32_t packkey(float v, uint32_t c) {
  return (__float_as_uint(v) & 0xFFFFFC00u) | c;
}
__device__ __forceinline__ float unpackkey(uint32_t m) {
  return __uint_as_float(m & 0xFFFFFC00u);
}

typedef __attribute__((address_space(1))) const uint32_t GU32;
typedef __attribute__((address_space(3))) uint32_t LU32;
__device__ __forceinline__ void gload_lds16(const void* g, void* l) {
  __builtin_amdgcn_global_load_lds((GU32*)g, (LU32*)l, 16, 0, 0);
}

// ---------------------------------------------------------------------------
// prep: swizzled chunk-major bf16 hi/lo We image (32 chunks x [hi 8K | lo 8K]),
// bias baked at k=100 (pad codes -1000); WdT transpose padded to stride 128;
// fix ctr = 0. Swizzle: byte L = c_local*256 + 2k stored at L ^ ((cl&7)<<4).
// ---------------------------------------------------------------------------
__global__ __launch_bounds__(256) void prep_k(
    const float* __restrict__ We, const float* __restrict__ be,
    const float* __restrict__ Wd, uint8_t* __restrict__ img,
    float* __restrict__ wdt, uint32_t* __restrict__ ctr) {
  int idx = blockIdx.x * 256 + threadIdx.x;
  if (idx == 0) *ctr = 0u;
  if (idx < 1024 * 128) {
    int c = idx >> 7, k = idx & 127;
    float v = 0.f;
    if (k < DIN) v = (c < DCODE) ? We[c * DIN + k] : 0.f;
    else if (k == DIN) v = (c < DCODE) ? be[c] : -1000.f;
    uint16_t h = f2bf(v);
    uint16_t l = f2bf(v - bf2f(h));
    int ch = c >> 5, cl = c & 31;
    int L = cl * 256 + k * 2;
    int S = L ^ ((cl & 7) << 4);
    uint8_t* base = img + ch * 16384;
    *(uint16_t*)(base + S) = h;
    *(uint16_t*)(base + 8192 + S) = l;
    wdt[idx] = (k < DIN && c < DCODE) ? Wd[k * DCODE + c] : 0.f;
  }
}

// ---------------------------------------------------------------------------
// screen_k (round-16 best): launch_bounds (512, 4) -> 4 waves/EU -> k =
// 4*4/8 = 2 blocks/CU = 16 waves/CU at VGPR 64 (no spills). T3/T4
// counted-vmcnt triple-buffer pipeline; 8 waves x 32 rows = 256 rows/block;
// 3x16KB chunk buffers, prefetch distance 2, s_waitcnt vmcnt(2) + raw
// s_barrier per chunk (full drain only at ch=30). Per chunk: 21 MFMA
// (7 K-steps x 3 hi/lo passes of 32x32x16), per-lane filter into 48-slot
// region of the row's d_out span.
// ---------------------------------------------------------------------------
__global__ __launch_bounds__(512, 4) void screen_k(
    const float* __restrict__ x, const uint8_t* __restrict__ img,
    uint32_t* __restrict__ cand) {
  __shared__ __align__(16) uint8_t sbuf[3][16384];
  int tid = threadIdx.x, lane = tid & 63, w = tid >> 6;
  int h = lane >> 5, r32 = lane & 31;
  int row = blockIdx.x * 256 + w * 32 + r32;

  // B fragments (x row, bf16 hi/lo), 7 ksteps of K=16 (this lane's 8-elem half)
  s16x8 Bh[7], Bl[7];
  const float* xr = x + (size_t)row * DIN;
  float sq = 0.f;
#pragma unroll
  for (int ks = 0; ks < 7; ++ks) {
    int k0 = ks * 16 + h * 8;
    float v[8];
    if (ks < 6) {
      float4 a = *(const float4*)(xr + k0);
      float4 b = *(const float4*)(xr + k0 + 4);
      v[0] = a.x; v[1] = a.y; v[2] = a.z; v[3] = a.w;
      v[4] = b.x; v[5] = b.y; v[6] = b.z; v[7] = b.w;
    } else if (h == 0) {              // k = 96..103: x96..99, bias, zeros
      float4 a = *(const float4*)(xr + 96);
      v[0] = a.x; v[1] = a.y; v[2] = a.z; v[3] = a.w;
      v[4] = 1.f; v[5] = 0.f; v[6] = 0.f; v[7] = 0.f;
    } else {                          // k = 104..111: zeros
#pragma unroll
      for (int j = 0; j < 8; ++j) v[j] = 0.f;
    }
    s16x8 hv, lv;
#pragma unroll
    for (int j = 0; j < 8; ++j) {
      sq = fmaf(v[j], v[j], sq);
      uint16_t hb = f2bf(v[j]);
      hv[j] = (short)hb;
      lv[j] = (short)f2bf(v[j] - bf2f(hb));
    }
    Bh[ks] = hv; Bl[ks] = lv;
  }
  sq += __shfl_xor(sq, 32);           // pair covers disjoint k-halves of the row
  float sr = sqrtf(sq);               // sqrt(||x||^2 + 1)
  float eb = 2e-5f * sr + 5e-5f;      // 3-pass screen error bound
  float t0 = ZTHR * 0.057735f * sr - eb;

  uint32_t tc = 0;
  uint32_t* rb = cand + (size_t)row * ROWU + h * RCAP;

  // prologue: stage chunks 0 and 1 (each wave stages its 2KB slice of each)
  {
    const uint8_t* s0 = img + w * 2048 + lane * 16;
    uint8_t* d0 = &sbuf[0][w * 2048 + lane * 16];
    gload_lds16(s0, d0);
    gload_lds16(s0 + 1024, d0 + 1024);
    const uint8_t* s1 = img + 16384 + w * 2048 + lane * 16;
    uint8_t* d1 = &sbuf[1][w * 2048 + lane * 16];
    gload_lds16(s1, d1);
    gload_lds16(s1 + 1024, d1 + 1024);
  }
  __syncthreads();

  for (int ch = 0; ch < 32; ++ch) {
    // stage chunk ch+2 into buf (ch+2)%3 (last read at iter ch-1; safe after
    // the end-of-(ch-1) barrier)
    if (ch < 30) {
      const uint8_t* src = img + (ch + 2) * 16384 + w * 2048 + lane * 16;
      uint8_t* dst = &sbuf[(ch + 2) % 3][w * 2048 + lane * 16];
      gload_lds16(src, dst);
      gload_lds16(src + 1024, dst + 1024);
    }
    const uint8_t* bb = sbuf[ch % 3];
    f32x16 acc = {};
#pragma unroll
    for (int ks = 0; ks < 7; ++ks) {
      int S = (r32 * 256 + ks * 32 + h * 16) ^ ((r32 & 7) << 4);
      s16x8 ah = *(const s16x8*)(bb + S);
      s16x8 al = *(const s16x8*)(bb + 8192 + S);
      acc = __builtin_amdgcn_mfma_f32_32x32x16_bf16(ah, Bh[ks], acc, 0, 0, 0);
      acc = __builtin_amdgcn_mfma_f32_32x32x16_bf16(ah, Bl[ks], acc, 0, 0, 0);
      acc = __builtin_amdgcn_mfma_f32_32x32x16_bf16(al, Bh[ks], acc, 0, 0, 0);
    }
    uint32_t cb = (uint32_t)(ch * 32 + 4 * h);
#pragma unroll
    for (int reg = 0; reg < 16; ++reg) {
      float v = acc[reg];
      if (v >= t0) {
        if (tc < (uint32_t)RCAP)
          rb[tc] = packkey(v, cb + (uint32_t)((reg & 3) + 8 * (reg >> 2)));
        tc++;
      }
    }
    // counted-vmcnt barrier: chunk ch+1's loads (issued at ch-1) are older
    // than this iter's 2 loads -> retired once outstanding <= 2. Only ch=30
    // (no new loads) needs a full drain for chunk 31.
    if (ch < 31) {
      if (ch == 30) asm volatile("s_waitcnt vmcnt(0)" ::: "memory");
      else          asm volatile("s_waitcnt vmcnt(2)" ::: "memory");
      __builtin_amdgcn_s_barrier();
    }
  }
  // header: counts for the two halves + thr + eb (one uint4 per row)
  uint32_t b0 = tc > 255u ? 255u : tc;
  uint32_t c1 = __shfl(b0, (lane & 31) + 32);
  if (lane < 32) {
    uint32_t* rowp = cand + (size_t)row * ROWU;
    float thr = t0 + 2.f * eb + 1e-3f;    // miss hazard + key trunc slack
    *(uint4*)(rowp + 96) = make_uint4(b0 | (c1 << 8), __float_as_uint(thr),
                                      __float_as_uint(eb), 0u);
  }
}

// ---------------------------------------------------------------------------
// select_decode_k: one row per HALF-WAVE (8 rows / 256-thr block). Two 48-slot
// regions per row; each lane owns 3 key slots; compaction + dynamic uint4 rank
// loop -> exact 25th key; fp64 re-rank only when >1 key in +-eps window;
// decode = 25 lanes x float4.
// ---------------------------------------------------------------------------
__global__ __launch_bounds__(256) void select_decode_k(
    const float* __restrict__ x, const float* __restrict__ We,
    const float* __restrict__ be, const float* __restrict__ bd,
    const float* __restrict__ wdt, float* __restrict__ out,
    uint32_t* __restrict__ fix_ctr, uint32_t* __restrict__ fix_list) {
  __shared__ uint32_t skeys[8][104];
  __shared__ uint2    selp[8][26];
  __shared__ double   wvalS[8][WCAP];
  __shared__ int      widS[8][WCAP];

  int tid = threadIdx.x, l32 = tid & 31, wi = tid >> 5;
  int lbase = (wi & 1) * 32;               // this half's bit offset in wave ballots
  uint32_t ltm32 = (l32 == 31) ? 0x7FFFFFFFu : ((1u << l32) - 1u);
  int row = blockIdx.x * 8 + wi;
  uint32_t* rowp = (uint32_t*)out + (size_t)row * ROWU;

  uint32_t hdr = rowp[96];
  float thrp = __uint_as_float(rowp[97]);
  float eb = __uint_as_float(rowp[98]);
  uint32_t c0 = hdr & 255u, c1 = (hdr >> 8) & 255u;
  uint32_t total = c0 + c1;
  bool bad = (c0 > (uint32_t)RCAP) || (c1 > (uint32_t)RCAP) || (total < 25u);

  uint32_t k0 = 0u, k1 = 0u, k2 = 0u, tau = 0u;
  int r0 = 0, r1 = 0, r2 = 0;
  float vtau = 0.f;
  if (!bad) {
    // slot -> (region, in-region idx): region0 = slots [0,48), region1 = [48,96)
    bool g1r0 = (l32 < 16);                        // slot 32+l32 in region0?
    uint32_t i0 = (uint32_t)l32;                   // region0
    uint32_t i1 = g1r0 ? (uint32_t)(32 + l32) : (uint32_t)(l32 - 16);
    uint32_t i2 = (uint32_t)(16 + l32);            // region1
    k0 = (i0 < c0) ? rowp[l32] : 0u;
    k1 = (i1 < (g1r0 ? c0 : c1)) ? rowp[32 + l32] : 0u;
    k2 = (i2 < c1) ? rowp[64 + l32] : 0u;
    // zero + compact (zeros inert: real keys are positive floats >= t0 > 0)
    skeys[wi][l32] = 0u; skeys[wi][32 + l32] = 0u; skeys[wi][64 + l32] = 0u;
    if (k0) skeys[wi][i0] = k0;
    if (k1) skeys[wi][(g1r0 ? 0u : c0) + i1] = k1;
    if (k2) skeys[wi][c0 + i2] = k2;
    // dynamic rank loop (~ceil(total/4) iters)
    int nq = ((int)total + 3) >> 2;
    const uint4* sp = (const uint4*)skeys[wi];
    for (int j = 0; j < nq; ++j) {
      uint4 q = sp[j];
      r0 += (q.x > k0) + (q.y > k0) + (q.z > k0) + (q.w > k0);
      r1 += (q.x > k1) + (q.y > k1) + (q.z > k1) + (q.w > k1);
      r2 += (q.x > k2) + (q.y > k2) + (q.z > k2) + (q.w > k2);
    }
    // tau = key of rank 24 (exists since total >= 25, keys unique)
    uint32_t h0 = (uint32_t)(__ballot(k0 != 0u && r0 == 24) >> lbase);
    uint32_t h1 = (uint32_t)(__ballot(k1 != 0u && r1 == 24) >> lbase);
    uint32_t h2 = (uint32_t)(__ballot(k2 != 0u && r2 == 24) >> lbase);
    if (h0)      tau = __shfl(k0, lbase + (__ffs(h0) - 1));
    else if (h1) tau = __shfl(k1, lbase + (__ffs(h1) - 1));
    else         tau = __shfl(k2, lbase + (__ffs(h2) - 1));
    vtau = unpackkey(tau);
    if (vtau < thrp) bad = true;           // possible missed-top-25 -> exact path
  }
  if (bad && l32 == 0) { uint32_t p = atomicAdd(fix_ctr, 1u); fix_list[p] = (uint32_t)row; }
  bool alive = !bad;

  float eps = 2.f * eb + 1e-3f;            // screen err both sides + key trunc
  float v0 = unpackkey(k0), v1 = unpackkey(k1), v2 = unpackkey(k2);
  bool in0 = k0 != 0u, in1 = k1 != 0u, in2 = k2 != 0u;
  bool w0 = in0 && fabsf(v0 - vtau) <= eps;
  bool w1 = in1 && fabsf(v1 - vtau) <= eps;
  bool w2 = in2 && fabsf(v2 - vtau) <= eps;
  uint32_t W0 = (uint32_t)(__ballot(w0) >> lbase);
  uint32_t W1 = (uint32_t)(__ballot(w1) >> lbase);
  uint32_t W2 = (uint32_t)(__ballot(w2) >> lbase);
  int nwin = __popc(W0) + __popc(W1) + __popc(W2);

  bool f0 = false, f1 = false, f2 = false;
  float fv0 = v0, fv1 = v1, fv2 = v2;
  bool bad2 = false;
  if (alive) {
    if (nwin == 1) {
      // window holds only tau itself: screen ranking is exact
      f0 = in0 && (r0 < 25); f1 = in1 && (r1 < 25); f2 = in2 && (r2 < 25);
    } else {
      bool s0 = in0 && (r0 < 25) && !w0;
      bool s1 = in1 && (r1 < 25) && !w1;
      bool s2 = in2 && (r2 < 25) && !w2;
      int ndef = __popc((uint32_t)(__ballot(s0) >> lbase)) +
                 __popc((uint32_t)(__ballot(s1) >> lbase)) +
                 __popc((uint32_t)(__ballot(s2) >> lbase));
      int need = 25 - ndef;
      if (nwin > WCAP || need < 0 || need > nwin) {
        bad2 = true;
      } else {
        int j0 = __popc(W0 & ltm32);
        int j1 = __popc(W0) + __popc(W1 & ltm32);
        int j2 = __popc(W0) + __popc(W1) + __popc(W2 & ltm32);
        if (w0) widS[wi][j0] = (int)(k0 & 1023u);
        if (w1) widS[wi][j1] = (int)(k1 & 1023u);
        if (w2) widS[wi][j2] = (int)(k2 & 1023u);
        const float* xr = x + (size_t)row * DIN;
        for (int j = 0; j < nwin; ++j) {
          int id = widS[wi][j];
          const float* wr = We + (size_t)id * DIN;
          double p = (double)xr[l32] * (double)wr[l32];
          p += (double)xr[l32 + 32] * (double)wr[l32 + 32];
          p += (double)xr[l32 + 64] * (double)wr[l32 + 64];
          if (l32 < 4) p += (double)xr[l32 + 96] * (double)wr[l32 + 96];
#pragma unroll
          for (int o = 1; o < 32; o <<= 1) p += __shfl_xor(p, o);
          if (l32 == 0) wvalS[wi][j] = p + (double)be[id];
        }
        uint32_t chosen = 0u;
        for (int j = 0; j < nwin; ++j) {
          double vj = wvalS[wi][j]; int idj = widS[wi][j];
          int rank = 0;
          for (int l2 = 0; l2 < nwin; ++l2) {
            double vl = wvalS[wi][l2]; int idl = widS[wi][l2];
            rank += (vl > vj || (vl == vj && idl < idj)) ? 1 : 0;
          }
          if (rank < need) chosen |= (1u << j);
        }
        bool ch0 = w0 && ((chosen >> j0) & 1u);
        bool ch1 = w1 && ((chosen >> j1) & 1u);
        bool ch2 = w2 && ((chosen >> j2) & 1u);
        if (ch0) fv0 = (float)wvalS[wi][j0];
        if (ch1) fv1 = (float)wvalS[wi][j1];
        if (ch2) fv2 = (float)wvalS[wi][j2];
        f0 = s0 || ch0; f1 = s1 || ch1; f2 = s2 || ch2;
      }
    }
  }
  if (bad2) {
    if (l32 == 0) { uint32_t p = atomicAdd(fix_ctr, 1u); fix_list[p] = (uint32_t)row; }
    alive = false;
  }

  if (l32 < 26) selp[wi][l32] = make_uint2(0u, 0u);
  uint32_t F0 = (uint32_t)(__ballot(alive && f0) >> lbase);
  uint32_t F1 = (uint32_t)(__ballot(alive && f1) >> lbase);
  uint32_t F2 = (uint32_t)(__ballot(alive && f2) >> lbase);
  int p0 = __popc(F0 & ltm32);
  int p1 = __popc(F0) + __popc(F1 & ltm32);
  int p2 = __popc(F0) + __popc(F1) + __popc(F2 & ltm32);
  if (alive && f0 && p0 < 25) selp[wi][p0] = make_uint2(__float_as_uint(fv0), k0 & 1023u);
  if (alive && f1 && p1 < 25) selp[wi][p1] = make_uint2(__float_as_uint(fv1), k1 & 1023u);
  if (alive && f2 && p2 < 25) selp[wi][p2] = make_uint2(__float_as_uint(fv2), k2 & 1023u);

  if (alive) {
    uint4 s4[13];
    const uint4* sq = (const uint4*)selp[wi];
#pragma unroll
    for (int j = 0; j < 13; ++j) s4[j] = sq[j];
    const uint32_t* sw = (const uint32_t*)s4;
    float4 a = make_float4(0.f, 0.f, 0.f, 0.f);
    if (l32 < 25) a = *(const float4*)(bd + 4 * l32);
#pragma unroll
    for (int j = 0; j < 25; ++j) {
      float v = __uint_as_float(sw[2 * j]);
      uint32_t id = sw[2 * j + 1];
      if (l32 < 25) {
        float4 wv = *(const float4*)(wdt + ((size_t)id << 7) + 4 * l32);
        a.x = fmaf(v, wv.x, a.x);
        a.y = fmaf(v, wv.y, a.y);
        a.z = fmaf(v, wv.z, a.z);
        a.w = fmaf(v, wv.w, a.w);
      }
    }
    if (l32 < 25) *(float4*)(out + (size_t)row * DIN + 4 * l32) = a;
  }
}

// ---------------------------------------------------------------------------
// fix_k: exact fp64 full pipeline for punted rows (expected few hundred).
// ---------------------------------------------------------------------------
__global__ __launch_bounds__(256) void fix_k(
    const float* __restrict__ x, const float* __restrict__ We,
    const float* __restrict__ be, const float* __restrict__ bd,
    const float* __restrict__ wdt, float* __restrict__ out,
    const uint32_t* __restrict__ fix_ctr, const uint32_t* __restrict__ fix_list) {
  __shared__ float xs[DIN];
  __shared__ unsigned long long keys[1024];
  __shared__ float dv[25];
  __shared__ int   di[25];
  int tid = threadIdx.x;
  int n = (int)*fix_ctr;
  for (int it = blockIdx.x; it < n; it += gridDim.x) {
    int row = (int)fix_list[it];
    __syncthreads();
    if (tid < DIN) xs[tid] = x[(size_t)row * DIN + tid];
    __syncthreads();
    for (int c = tid; c < 1024; c += 256) {
      unsigned long long kk = 0ull;
      if (c < DCODE) {
        double a = 0.0;
        for (int k = 0; k < DIN; ++k)
          a = fma((double)xs[k], (double)We[(size_t)c * DIN + k], a);
        a += (double)be[c];
        unsigned long long uu = (unsigned long long)__double_as_longlong(a);
        uu ^= ((unsigned long long)((long long)uu >> 63)) | 0x8000000000000000ull;
        kk = (uu & ~1023ull) | (unsigned long long)c;
      }
      keys[c] = kk;
    }
    __syncthreads();
    if (tid < 64) {
      for (int p = 0; p < 25; ++p) {
        unsigned long long mx = 0ull;
        for (int j = 0; j < 16; ++j) {
          unsigned long long v = keys[tid * 16 + j];
          if (v > mx) mx = v;
        }
#pragma unroll
        for (int off = 32; off > 0; off >>= 1) {
          unsigned long long o = (unsigned long long)__shfl_xor((long long)mx, off, 64);
          if (o > mx) mx = o;
        }
        if (tid == 0) {
          int id = (int)(mx & 1023ull);
          unsigned long long ub =
              (mx & 0x8000000000000000ull) ? (mx & 0x7FFFFFFFFFFFFFFFull) : ~mx;
          dv[p] = (float)__longlong_as_double((long long)ub);
          di[p] = id;
          keys[id] = 0ull;
        }
      }
    }
    __syncthreads();
    if (tid < DIN) {
      float a = bd[tid];
      for (int p = 0; p < 25; ++p)
        a = fmaf(dv[p], wdt[((size_t)di[p] << 7) + tid], a);
      out[(size_t)row * DIN + tid] = a;
    }
  }
}

// ============================================================================
// Fallback path (round-1, known-pass)
// ============================================================================
__global__ __launch_bounds__(256) void transpose_wdec_k(const float* __restrict__ Wd,
                                                        float* __restrict__ WdT) {
  int idx = blockIdx.x * 256 + threadIdx.x;
  if (idx < DIN * DCODE) {
    int c = idx / DIN;
    int j = idx - c * DIN;
    WdT[idx] = Wd[j * DCODE + c];
  }
}

#define FKEEP 28
__global__ __launch_bounds__(256) void sae_topk_fused(
    const float* __restrict__ x, const float* __restrict__ We,
    const float* __restrict__ be, const float* __restrict__ Wd,
    const float* __restrict__ bd, const float* __restrict__ WdT,
    float* __restrict__ out, int nrows) {
  int row = blockIdx.x * 256 + threadIdx.x;
  if (row >= nrows) return;
  float xv[DIN];
  {
    const float4* x4 = reinterpret_cast<const float4*>(x + (size_t)row * DIN);
#pragma unroll
    for (int i = 0; i < DIN / 4; ++i) {
      float4 v = x4[i];
      xv[4 * i] = v.x; xv[4 * i + 1] = v.y; xv[4 * i + 2] = v.z; xv[4 * i + 3] = v.w;
    }
  }
  uint32_t keys[FKEEP];
#pragma unroll
  for (int j = 0; j < FKEEP; ++j) keys[j] = 0u;
  for (int c = 0; c < DCODE; ++c) {
    const float4* w4 = reinterpret_cast<const float4*>(We + c * DIN);
    float pp0 = be[c], pp1 = 0.f, pp2 = 0.f, pp3 = 0.f;
#pragma unroll
    for (int i = 0; i < DIN / 4; ++i) {
      float4 wv = w4[i];
      pp0 = fmaf(wv.x, xv[4 * i], pp0);
      pp1 = fmaf(wv.y, xv[4 * i + 1], pp1);
      pp2 = fmaf(wv.z, xv[4 * i + 2], pp2);
      pp3 = fmaf(wv.w, xv[4 * i + 3], pp3);
    }
    float h = (pp0 + pp1) + (pp2 + pp3);
    uint32_t u = __float_as_uint(h);
    u ^= ((uint32_t)((int32_t)u >> 31)) | 0x80000000u;
    uint32_t key = (u & 0xFFFFFC00u) | (uint32_t)c;
    if (key > keys[FKEEP - 1]) {
#pragma unroll
      for (int j = FKEEP - 1; j > 0; --j)
        keys[j] = (key > keys[j]) ? ((key > keys[j - 1]) ? keys[j - 1] : key) : keys[j];
      keys[0] = (key > keys[0]) ? key : keys[0];
    }
  }
  double v64[FKEEP];
#pragma unroll
  for (int kq = 0; kq < FKEEP; ++kq) {
    int c = (int)(keys[kq] & 1023u);
    const float4* w4 = reinterpret_cast<const float4*>(We + c * DIN);
    double aa0 = 0.0, aa1 = 0.0;
#pragma unroll
    for (int i = 0; i < DIN / 4; ++i) {
      float4 wv = w4[i];
      aa0 = fma((double)wv.x, (double)xv[4 * i], aa0);
      aa1 = fma((double)wv.y, (double)xv[4 * i + 1], aa1);
      aa0 = fma((double)wv.z, (double)xv[4 * i + 2], aa0);
      aa1 = fma((double)wv.w, (double)xv[4 * i + 3], aa1);
    }
    double h = (aa0 + aa1) + (double)be[c];
    uint64_t u = (uint64_t)__double_as_longlong(h);
    u = (u & ~1023ull) | (uint64_t)(uint32_t)c;
    v64[kq] = __longlong_as_double((int64_t)u);
  }
#pragma unroll
  for (int p = 0; p < FKEEP - 1; ++p) {
#pragma unroll
    for (int j = 0; j < FKEEP - 1 - p; ++j) {
      double a = v64[j], b2 = v64[j + 1];
      v64[j] = fmax(a, b2);
      v64[j + 1] = fmin(a, b2);
    }
  }
  float acc[DIN];
  {
    const float4* b4 = reinterpret_cast<const float4*>(bd);
#pragma unroll
    for (int i = 0; i < DIN / 4; ++i) {
      float4 v = b4[i];
      acc[4 * i] = v.x; acc[4 * i + 1] = v.y; acc[4 * i + 2] = v.z; acc[4 * i + 3] = v.w;
    }
  }
  if (WdT) {
#pragma unroll
    for (int kq = 0; kq < 25; ++kq) {
      int c = (int)((uint64_t)__double_as_longlong(v64[kq]) & 1023ull);
      float hv = (float)v64[kq];
      const float4* w4 = reinterpret_cast<const float4*>(WdT + c * DIN);
#pragma unroll
      for (int i = 0; i < DIN / 4; ++i) {
        float4 wv = w4[i];
        acc[4 * i]     = fmaf(hv, wv.x, acc[4 * i]);
        acc[4 * i + 1] = fmaf(hv, wv.y, acc[4 * i + 1]);
        acc[4 * i + 2] = fmaf(hv, wv.z, acc[4 * i + 2]);
        acc[4 * i + 3] = fmaf(hv, wv.w, acc[4 * i + 3]);
      }
    }
  } else {
#pragma unroll
    for (int kq = 0; kq < 25; ++kq) {
      int c = (int)((uint64_t)__double_as_longlong(v64[kq]) & 1023ull);
      float hv = (float)v64[kq];
      for (int j = 0; j < DIN; ++j)
        acc[j] = fmaf(hv, Wd[j * DCODE + c], acc[j]);
    }
  }
  float4* o4 = reinterpret_cast<float4*>(out + (size_t)row * DIN);
#pragma unroll
  for (int i = 0; i < DIN / 4; ++i)
    o4[i] = make_float4(acc[4 * i], acc[4 * i + 1], acc[4 * i + 2], acc[4 * i + 3]);
}

// ============================================================================
extern "C" void kernel_launch(void* const* d_in, const int* in_sizes, int n_in,
                              void* d_out, int out_size, void* d_ws, size_t ws_size,
                              hipStream_t stream) {
  const float* x  = (const float*)d_in[0];
  const float* We = (const float*)d_in[1];
  const float* be = (const float*)d_in[2];
  const float* Wd = (const float*)d_in[3];
  const float* bd = (const float*)d_in[4];
  int nrows = in_sizes[0] / DIN;

  bool shape_ok = (in_sizes[1] == DCODE * DIN) && (in_sizes[2] == DCODE) &&
                  (in_sizes[3] == DIN * DCODE) && (nrows % 256 == 0) &&
                  (nrows <= 131072);
  if (shape_ok && ws_size >= (size_t)WS_NEED) {
    char* wsb = (char*)d_ws;
    uint32_t* ctr = (uint32_t*)(wsb + OFF_CTR);
    uint32_t* lst = (uint32_t*)(wsb + OFF_LST);
    uint8_t*  img = (uint8_t*)(wsb + OFF_IMG);
    float*    wdt = (float*)(wsb + OFF_WDT);

    prep_k<<<512, 256, 0, stream>>>(We, be, Wd, img, wdt, ctr);
    screen_k<<<nrows / 256, 512, 0, stream>>>(x, img, (uint32_t*)d_out);
    select_decode_k<<<nrows / 8, 256, 0, stream>>>(x, We, be, bd, wdt, (float*)d_out, ctr, lst);
    fix_k<<<512, 256, 0, stream>>>(x, We, be, bd, wdt, (float*)d_out, ctr, lst);
  } else {
    float* WdT = nullptr;
    if (ws_size >= (size_t)(DIN * DCODE * sizeof(float))) {
      WdT = (float*)d_ws;
      transpose_wdec_k<<<(DIN * DCODE + 255) / 256, 256, 0, stream>>>(Wd, WdT);
    }
    int nb = (nrows + 255) / 256;
    sae_topk_fused<<<nb, 256, 0, stream>>>(x, We, be, Wd, bd, WdT, (float*)d_out, nrows);
  }
}